// Round 2
// baseline (640.842 us; speedup 1.0000x reference)
//
#include <hip/hip_runtime.h>

// MaxPoolAggregator: out[q, :] = max over s of features[nbrs[q,s], :]
// features: float32 [N_NODES, 128]   (512 B per row)
// nbrs:     int32   [N_QUERY, S]
// out:      float32 [N_QUERY, 128]
//
// Design: 32 threads per query, each owns one float4 (16 B) chunk of the
// 512 B row. Each 32-lane group reads a full row contiguously
// (global_load_dwordx4, coalesced); a wave writes 2 queries = 1 KB
// contiguous. S=10 unrolled -> 10 independent loads in flight per thread.
// Memory-bound: ~567 MB/launch -> ~90 us floor at 6.3 TB/s.

typedef __attribute__((ext_vector_type(4))) float f32x4;

template <int S>
__global__ __launch_bounds__(256) void maxpool_s(
    const float* __restrict__ feats,   // 128 floats per row
    const int* __restrict__ nbrs,
    float* __restrict__ out,
    int n_query)
{
    int idx = blockIdx.x * blockDim.x + threadIdx.x;
    int q = idx >> 5;          // query id
    int g = idx & 31;          // float4 chunk within the 128-float row
    if (q >= n_query) return;

    const long base = (long)q * S;

    f32x4 m;
    {
        int nbr = nbrs[base];
        m = *((const f32x4*)(feats + (size_t)nbr * 128) + g);
    }
    #pragma unroll
    for (int s = 1; s < S; ++s) {
        int nbr = nbrs[base + s];
        f32x4 v = *((const f32x4*)(feats + (size_t)nbr * 128) + g);
        m[0] = fmaxf(m[0], v[0]);
        m[1] = fmaxf(m[1], v[1]);
        m[2] = fmaxf(m[2], v[2]);
        m[3] = fmaxf(m[3], v[3]);
    }

    *((f32x4*)(out + (size_t)q * 128) + g) = m;
}

__global__ __launch_bounds__(256) void maxpool_generic(
    const float* __restrict__ feats,
    const int* __restrict__ nbrs,
    float* __restrict__ out,
    int n_query, int num_sample)
{
    int idx = blockIdx.x * blockDim.x + threadIdx.x;
    int q = idx >> 5;
    int g = idx & 31;
    if (q >= n_query) return;

    const long base = (long)q * num_sample;

    f32x4 m;
    {
        int nbr = nbrs[base];
        m = *((const f32x4*)(feats + (size_t)nbr * 128) + g);
    }
    for (int s = 1; s < num_sample; ++s) {
        int nbr = nbrs[base + s];
        f32x4 v = *((const f32x4*)(feats + (size_t)nbr * 128) + g);
        m[0] = fmaxf(m[0], v[0]);
        m[1] = fmaxf(m[1], v[1]);
        m[2] = fmaxf(m[2], v[2]);
        m[3] = fmaxf(m[3], v[3]);
    }

    *((f32x4*)(out + (size_t)q * 128) + g) = m;
}

extern "C" void kernel_launch(void* const* d_in, const int* in_sizes, int n_in,
                              void* d_out, int out_size, void* d_ws, size_t ws_size,
                              hipStream_t stream) {
    const float* feats = (const float*)d_in[0];
    const int*   nbrs  = (const int*)d_in[1];
    float*       out   = (float*)d_out;

    const int D = 128;                           // feature dim per reference
    int n_query = out_size / D;
    int num_sample = (n_query > 0) ? (in_sizes[1] / n_query) : 1;

    int total = n_query * 32;                    // 32 threads per query (16B chunks)
    int blocks = (total + 255) / 256;

    if (num_sample == 10) {
        maxpool_s<10><<<blocks, 256, 0, stream>>>(feats, nbrs, out, n_query);
    } else {
        maxpool_generic<<<blocks, 256, 0, stream>>>(feats, nbrs, out, n_query, num_sample);
    }
}